// Round 8
// baseline (242.879 us; speedup 1.0000x reference)
//
#include <hip/hip_runtime.h>

#define C 64
#define K 1024
#define HW 4096
#define N_TOTAL 131072   // 32*64*64
#define OUT0 8388608     // 32*64*64*64 (z_q_out elements)
#define MT 128           // n-rows per block
#define KT 128           // codes per K-tile
#define NTILES (K / KT)

// d_ws float layout
#define WS_EK        0
#define WS_PARTIALS  1024
#define WS_ETG       3072                 // 64*1024 floats
#define WS_NEED_FLOATS (3072 + C * K)

typedef unsigned int u32;
typedef unsigned long long u64;

// monotone float map + index pack: lexicographic min == (min d, then min k)
__device__ __forceinline__ u64 packdk(float d, int k) {
    u32 b = __float_as_uint(d);
    u32 m = b ^ ((u32)((int)b >> 31) | 0x80000000u);
    return ((u64)m << 32) | (u32)k;
}

// ---------------------------------------------------------------------------
// Kernel 1 (main path): E prep. ek = ||e_k||^2 numpy pairwise-8 (FROZEN) +
// transpose E into Etg[c][k] so vq_main's LDS staging is a layout-preserving
// coalesced copy.
// ---------------------------------------------------------------------------
__global__ __launch_bounds__(256) void eprep_kernel(const float* __restrict__ E,
                                                    float* __restrict__ Etg,
                                                    float* __restrict__ ek) {
#pragma clang fp contract(off)
    int k = blockIdx.x * 256 + threadIdx.x;
    const float* e = E + k * C;
    float ev[C];
#pragma unroll
    for (int c4 = 0; c4 < 16; ++c4) {
        float4 v = *(const float4*)(e + c4 * 4);
        ev[c4 * 4 + 0] = v.x; ev[c4 * 4 + 1] = v.y;
        ev[c4 * 4 + 2] = v.z; ev[c4 * 4 + 3] = v.w;
    }
    float r[8];
#pragma unroll
    for (int j = 0; j < 8; ++j) r[j] = ev[j] * ev[j];
#pragma unroll
    for (int i = 8; i < C; i += 8)
#pragma unroll
        for (int j = 0; j < 8; ++j) r[j] += ev[i + j] * ev[i + j];
    ek[k] = ((r[0] + r[1]) + (r[2] + r[3])) + ((r[4] + r[5]) + (r[6] + r[7]));
#pragma unroll
    for (int c = 0; c < C; ++c) Etg[c * K + k] = ev[c];   // coalesced per c
}

// ---------------------------------------------------------------------------
// Kernel 2 (main path): register-blocked VALU GEMM argmin + fused epilogue.
// R7 post-mortem: 8x4 tile = 1.5 LDS-bytes/fma -> ~50 MB LDS reads/CU ->
// ~245 us LDS-port-bound (measured 233, VALUBusy 76%, conflicts ~0).
// Fix: 8n x 8q tile (1.0 B/fma, R4-proven to compile at VGPR=128) + cheap
// staging (layout-preserving copy from Etg) + T14 async split: next tile's
// 8 global float4 loads issue BEFORE the 64-c compute phase (~8.7K cyc
// hides L2 latency), ds_write after the read-barrier.
// Per c-step: 4 ds_read_b128 + 64 fma.  LDS 68 KB -> 2 blocks/CU.
// Numerics FROZEN (absmax 0.0 R1-R7): sequential fma c=0..63 per (n,k);
// d = fmaf(-2,acc,fl(zn+ek)); ascending-k strict <; R4-verified lane
// mapping, k-decode, and u64 lexicographic cross-thread reduce.
// ---------------------------------------------------------------------------
__global__ __launch_bounds__(256, 2) void vq_main(const float* __restrict__ Z,
                                                  const float* __restrict__ E,
                                                  const float* __restrict__ Etg,
                                                  const float* __restrict__ ek,
                                                  float* __restrict__ out,
                                                  float* __restrict__ partials) {
#pragma clang fp contract(off)
    __shared__ float Zt[C * MT];     // [c][n_local]  32 KB
    __shared__ float EtS[C * KT];    // [c][k_local]  32 KB
    __shared__ float znbuf[MT];
    __shared__ u64 red[4][8][8];     // [wave][i_l][m]

    const int t = threadIdx.x;
    const int n0 = blockIdx.x * MT;
    const int b = n0 >> 12;
    const int hw0 = n0 & 4095;
    const float* zbase = Z + b * (C * HW) + hw0;

    // ---- stage Zt (coalesced; Z is already [c][n]-contiguous) ------------
#pragma unroll
    for (int r = 0; r < 8; ++r) {
        int idx4 = r * 256 + t;
        int c = idx4 >> 5, n4 = idx4 & 31;
        float4 v = *(const float4*)(zbase + c * HW + n4 * 4);
        *(float4*)(&Zt[c * MT + n4 * 4]) = v;
    }
    // ---- stage EtS for tile 0 (layout-preserving copy from Etg) ----------
#pragma unroll
    for (int p = 0; p < 8; ++p) {
        int idx = p * 256 + t;
        int c = idx >> 5, k4 = idx & 31;
        float4 v = *(const float4*)(Etg + c * K + k4 * 4);
        *(float4*)(&EtS[c * KT + k4 * 4]) = v;
    }
    __syncthreads();

    // ---- zn per row (numpy pairwise-8 order, FROZEN) ----
    if (t < MT) {
        float r8[8];
#pragma unroll
        for (int j = 0; j < 8; ++j) { float v = Zt[j * MT + t]; r8[j] = v * v; }
#pragma unroll
        for (int i = 1; i < 8; ++i)
#pragma unroll
            for (int j = 0; j < 8; ++j) { float v = Zt[(i * 8 + j) * MT + t]; r8[j] += v * v; }
        znbuf[t] = ((r8[0] + r8[1]) + (r8[2] + r8[3])) + ((r8[4] + r8[5]) + (r8[6] + r8[7]));
    }
    __syncthreads();

    const int wave = t >> 6, lane = t & 63;
    const int i_l = lane & 7, j_l = lane >> 3;
    const int ig = ((wave & 1) << 3) | i_l;    // n-group 0..15 (rows ig*8..+8)
    const int jg = ((wave >> 1) << 3) | j_l;   // k-group 0..15 (codes jg*8..+8)

    float znm[8];
#pragma unroll
    for (int m = 0; m < 8; ++m) znm[m] = znbuf[ig * 8 + m];

    float dmin[8];
    int qb[8];
#pragma unroll
    for (int m = 0; m < 8; ++m) { dmin[m] = __builtin_inff(); qb[m] = 0; }

#pragma unroll 1
    for (int tile = 0; tile < NTILES; ++tile) {
        // ---- T14 async split: issue next tile's global loads NOW ----
        float4 pv[8];
        const bool hasNext = (tile + 1 < NTILES);
        if (hasNext) {
            const float* src = Etg + (tile + 1) * KT;
#pragma unroll
            for (int p = 0; p < 8; ++p) {
                int idx = p * 256 + t;
                int c = idx >> 5, k4 = idx & 31;
                pv[p] = *(const float4*)(src + c * K + k4 * 4);
            }
        }

        float ekq[8];
        {
            const float* ekp = ek + tile * KT + jg * 8;
            float4 a = *(const float4*)ekp;
            float4 bq = *(const float4*)(ekp + 4);
            ekq[0] = a.x;  ekq[1] = a.y;  ekq[2] = a.z;  ekq[3] = a.w;
            ekq[4] = bq.x; ekq[5] = bq.y; ekq[6] = bq.z; ekq[7] = bq.w;
        }

        float acc[8][8];
#pragma unroll
        for (int m = 0; m < 8; ++m)
#pragma unroll
            for (int q = 0; q < 8; ++q) acc[m][q] = 0.0f;

#pragma unroll 4
        for (int c = 0; c < C; ++c) {
            float4 za = *(const float4*)(&Zt[c * MT + ig * 8]);
            float4 zb = *(const float4*)(&Zt[c * MT + ig * 8 + 4]);
            float4 ea = *(const float4*)(&EtS[c * KT + jg * 8]);
            float4 eb = *(const float4*)(&EtS[c * KT + jg * 8 + 4]);
            float zm[8] = {za.x, za.y, za.z, za.w, zb.x, zb.y, zb.z, zb.w};
            float eq[8] = {ea.x, ea.y, ea.z, ea.w, eb.x, eb.y, eb.z, eb.w};
#pragma unroll
            for (int m = 0; m < 8; ++m)
#pragma unroll
                for (int q = 0; q < 8; ++q)
                    acc[m][q] = __builtin_fmaf(zm[m], eq[q], acc[m][q]);
        }

        const int qbase = tile * 8;
#pragma unroll
        for (int m = 0; m < 8; ++m)
#pragma unroll
            for (int q = 0; q < 8; ++q) {
                float A = znm[m] + ekq[q];                     // fl(zn+ek)
                float d = __builtin_fmaf(-2.0f, acc[m][q], A); // == fl(A-2a), 2a exact
                if (d < dmin[m]) { dmin[m] = d; qb[m] = qbase + q; }
            }

        __syncthreads();   // all waves done READING EtS
        if (hasNext) {
#pragma unroll
            for (int p = 0; p < 8; ++p) {
                int idx = p * 256 + t;
                int c = idx >> 5, k4 = idx & 31;
                *(float4*)(&EtS[c * KT + k4 * 4]) = pv[p];
            }
        }
        __syncthreads();   // EtS ready for next tile
    }

    // decode per-thread k, pack to (mono(d),k), reduce (R4-verified path)
    u64 bestp[8];
#pragma unroll
    for (int m = 0; m < 8; ++m) {
        int q8 = qb[m];
        int k = ((q8 >> 3) << 7) + jg * 8 + (q8 & 7);
        bestp[m] = packdk(dmin[m], k);
    }
#pragma unroll
    for (int m = 0; m < 8; ++m) {
        u64 v = bestp[m];
#pragma unroll
        for (int mask = 8; mask <= 32; mask <<= 1) {
            u64 o = __shfl_xor(v, mask, 64);
            v = o < v ? o : v;
        }
        bestp[m] = v;
    }
    if (j_l == 0) {
#pragma unroll
        for (int m = 0; m < 8; ++m) red[wave][i_l][m] = bestp[m];
    }
    __syncthreads();

    // ---- fused epilogue: thread t<128 owns row t (FROZEN body/order) ----
    if (t < MT) {
        int igg = t >> 3, m = t & 7;
        int ihalf = igg >> 3, iw = igg & 7;   // waves {ihalf, ihalf+2} hold it
        u64 a = red[ihalf][iw][m];
        u64 b2 = red[ihalf + 2][iw][m];
        u64 v = b2 < a ? b2 : a;
        int best = (int)(v & 0xFFFFFFFFu);
        int n = n0 + t;
        out[OUT0 + n] = (float)best;

        const float4* eb4 = (const float4*)(E + best * C);
        float* o0 = out + b * (C * HW) + hw0 + t;
        float ls = 0.0f;
#pragma unroll
        for (int c4 = 0; c4 < 16; ++c4) {
            float4 e4 = eb4[c4];
            int cb = c4 * 4;
            float z0 = Zt[(cb + 0) * MT + t], z1 = Zt[(cb + 1) * MT + t];
            float z2 = Zt[(cb + 2) * MT + t], z3 = Zt[(cb + 3) * MT + t];
            float f0 = e4.x - z0; o0[(cb + 0) * HW] = z0 + f0; ls += f0 * f0;
            float f1 = e4.y - z1; o0[(cb + 1) * HW] = z1 + f1; ls += f1 * f1;
            float f2 = e4.z - z2; o0[(cb + 2) * HW] = z2 + f2; ls += f2 * f2;
            float f3 = e4.w - z3; o0[(cb + 3) * HW] = z3 + f3; ls += f3 * f3;
        }
#pragma unroll
        for (int off = 32; off > 0; off >>= 1) ls += __shfl_xor(ls, off, 64);
        if ((t & 63) == 0) partials[n >> 6] = ls;
    }
}

// ---------------------------------------------------------------------------
// Fallback path kernels (tiny ws): R2/R4 structure, FROZEN.
// ---------------------------------------------------------------------------
__global__ __launch_bounds__(256) void ek_kernel(const float* __restrict__ E,
                                                 float* __restrict__ ek) {
#pragma clang fp contract(off)
    int k = blockIdx.x * 256 + threadIdx.x;
    if (k >= K) return;
    const float* e = E + k * C;
    float r[8];
#pragma unroll
    for (int j = 0; j < 8; ++j) { float v = e[j]; r[j] = v * v; }
#pragma unroll
    for (int i = 8; i < C; i += 8) {
#pragma unroll
        for (int j = 0; j < 8; ++j) { float v = e[i + j]; r[j] += v * v; }
    }
    ek[k] = ((r[0] + r[1]) + (r[2] + r[3])) + ((r[4] + r[5]) + (r[6] + r[7]));
}

__global__ __launch_bounds__(256, 4) void vq_combined(const float* __restrict__ Z,
                                                      const float* __restrict__ E,
                                                      const float* __restrict__ ek,
                                                      float* __restrict__ out,
                                                      float* __restrict__ partials) {
#pragma clang fp contract(off)
    int n = blockIdx.x * 256 + threadIdx.x;
    int b = n >> 12;
    int hw = n & 4095;
    const float* zp = Z + b * (C * HW) + hw;

    float z[C];
#pragma unroll
    for (int c = 0; c < C; ++c) z[c] = zp[c * HW];
    float zn;
    {
        float r[8];
#pragma unroll
        for (int j = 0; j < 8; ++j) r[j] = z[j] * z[j];
#pragma unroll
        for (int i = 8; i < C; i += 8) {
#pragma unroll
            for (int j = 0; j < 8; ++j) r[j] += z[i + j] * z[i + j];
        }
        zn = ((r[0] + r[1]) + (r[2] + r[3])) + ((r[4] + r[5]) + (r[6] + r[7]));
    }

    float dmin = __builtin_inff();
    int best = 0;
#pragma unroll 1
    for (int k = 0; k < K; k += 4) {
        const float* e0 = E + k * C;
        float a0 = 0.0f, a1 = 0.0f, a2 = 0.0f, a3 = 0.0f;
#pragma unroll
        for (int c = 0; c < C; ++c) {
            float zc = z[c];
            a0 = __builtin_fmaf(zc, e0[c], a0);
            a1 = __builtin_fmaf(zc, e0[C + c], a1);
            a2 = __builtin_fmaf(zc, e0[2 * C + c], a2);
            a3 = __builtin_fmaf(zc, e0[3 * C + c], a3);
        }
        float A0 = zn + ek[k],     A1 = zn + ek[k + 1];
        float A2 = zn + ek[k + 2], A3 = zn + ek[k + 3];
        float d0 = A0 - 2.0f * a0, d1 = A1 - 2.0f * a1;
        float d2 = A2 - 2.0f * a2, d3 = A3 - 2.0f * a3;
        if (d0 < dmin) { dmin = d0; best = k; }
        if (d1 < dmin) { dmin = d1; best = k + 1; }
        if (d2 < dmin) { dmin = d2; best = k + 2; }
        if (d3 < dmin) { dmin = d3; best = k + 3; }
    }

    const float4* eb4 = (const float4*)(E + best * C);
    float* o0 = out + b * (C * HW) + hw;
    float ls = 0.0f;
#pragma unroll
    for (int c4 = 0; c4 < 16; ++c4) {
        float4 e4 = eb4[c4];
        int cb = c4 * 4;
        float f0 = e4.x - z[cb + 0]; o0[(cb + 0) * HW] = z[cb + 0] + f0; ls += f0 * f0;
        float f1 = e4.y - z[cb + 1]; o0[(cb + 1) * HW] = z[cb + 1] + f1; ls += f1 * f1;
        float f2 = e4.z - z[cb + 2]; o0[(cb + 2) * HW] = z[cb + 2] + f2; ls += f2 * f2;
        float f3 = e4.w - z[cb + 3]; o0[(cb + 3) * HW] = z[cb + 3] + f3; ls += f3 * f3;
    }
    out[OUT0 + n] = (float)best;
#pragma unroll
    for (int off = 32; off > 0; off >>= 1) ls += __shfl_xor(ls, off, 64);
    if ((threadIdx.x & 63) == 0) partials[n >> 6] = ls;
}

// ---------------------------------------------------------------------------
// Final loss reduction in fp64 (FROZEN).
// ---------------------------------------------------------------------------
__global__ __launch_bounds__(256) void loss_kernel(const float* __restrict__ partials,
                                                   float* __restrict__ out) {
    __shared__ double sm[256];
    int t = threadIdx.x;
    double s = 0.0;
    for (int i = t; i < (N_TOTAL / 64); i += 256) s += (double)partials[i];
    sm[t] = s;
    __syncthreads();
    for (int o = 128; o > 0; o >>= 1) {
        if (t < o) sm[t] += sm[t + o];
        __syncthreads();
    }
    if (t == 0) {
        float m = (float)(sm[0] * (1.0 / 8388608.0));
        float loss = m + 0.25f * m;
        out[OUT0 + N_TOTAL] = loss;
    }
}

extern "C" void kernel_launch(void* const* d_in, const int* in_sizes, int n_in,
                              void* d_out, int out_size, void* d_ws, size_t ws_size,
                              hipStream_t stream) {
    const float* Z = (const float*)d_in[0];
    const float* E = (const float*)d_in[1];
    float* out = (float*)d_out;
    float* ws = (float*)d_ws;
    float* ek = ws + WS_EK;
    float* partials = ws + WS_PARTIALS;

    if (ws_size >= (size_t)WS_NEED_FLOATS * sizeof(float)) {
        float* Etg = ws + WS_ETG;
        hipLaunchKernelGGL(eprep_kernel, dim3(K / 256), dim3(256), 0, stream,
                           E, Etg, ek);
        hipLaunchKernelGGL(vq_main, dim3(N_TOTAL / MT), dim3(256), 0, stream,
                           Z, E, Etg, ek, out, partials);
    } else {
        hipLaunchKernelGGL(ek_kernel, dim3(4), dim3(256), 0, stream, E, ek);
        hipLaunchKernelGGL(vq_combined, dim3(N_TOTAL / 256), dim3(256), 0, stream,
                           Z, E, ek, out, partials);
    }
    hipLaunchKernelGGL(loss_kernel, dim3(1), dim3(256), 0, stream, partials, out);
}

// Round 9
// 219.951 us; speedup vs baseline: 1.1042x; 1.1042x over previous
//
#include <hip/hip_runtime.h>

#define C 64
#define K 1024
#define HW 4096
#define N_TOTAL 131072   // 32*64*64
#define OUT0 8388608     // 32*64*64*64 (z_q_out elements)
#define MT 128           // n-rows per block
#define KT 128           // codes per K-tile
#define NTILES (K / KT)

// d_ws float layout
#define WS_EK        0
#define WS_PARTIALS  1024
#define WS_ETG       3072                 // 64*1024 floats
#define WS_NEED_FLOATS (3072 + C * K)

typedef unsigned int u32;
typedef unsigned long long u64;
typedef const __attribute__((address_space(1))) void* gas_ptr;
typedef __attribute__((address_space(3))) void* las_ptr;

// monotone float map + index pack: lexicographic min == (min d, then min k)
__device__ __forceinline__ u64 packdk(float d, int k) {
    u32 b = __float_as_uint(d);
    u32 m = b ^ ((u32)((int)b >> 31) | 0x80000000u);
    return ((u64)m << 32) | (u32)k;
}

// ---------------------------------------------------------------------------
// Kernel 1 (main path): E prep. ek = ||e_k||^2 numpy pairwise-8 (FROZEN) +
// transpose E into Etg[c][k] so vq_main's LDS staging is row-linear (the
// exact contiguous pattern global_load_lds requires).
// ---------------------------------------------------------------------------
__global__ __launch_bounds__(256) void eprep_kernel(const float* __restrict__ E,
                                                    float* __restrict__ Etg,
                                                    float* __restrict__ ek) {
#pragma clang fp contract(off)
    int k = blockIdx.x * 256 + threadIdx.x;
    const float* e = E + k * C;
    float ev[C];
#pragma unroll
    for (int c4 = 0; c4 < 16; ++c4) {
        float4 v = *(const float4*)(e + c4 * 4);
        ev[c4 * 4 + 0] = v.x; ev[c4 * 4 + 1] = v.y;
        ev[c4 * 4 + 2] = v.z; ev[c4 * 4 + 3] = v.w;
    }
    float r[8];
#pragma unroll
    for (int j = 0; j < 8; ++j) r[j] = ev[j] * ev[j];
#pragma unroll
    for (int i = 8; i < C; i += 8)
#pragma unroll
        for (int j = 0; j < 8; ++j) r[j] += ev[i + j] * ev[i + j];
    ek[k] = ((r[0] + r[1]) + (r[2] + r[3])) + ((r[4] + r[5]) + (r[6] + r[7]));
#pragma unroll
    for (int c = 0; c < C; ++c) Etg[c * K + k] = ev[c];   // coalesced per c
}

// ---------------------------------------------------------------------------
// Kernel 2 (main path): register-blocked VALU GEMM argmin + fused epilogue.
// R8 post-mortem: pv[8] prefetch regs (32 VGPR) on top of acc[64] -> spill
// (WRITE_SIZE 139MB at VGPR=104). Lesson (R5/R6/R8): staging through VGPRs
// alongside a 64-reg accumulator breaks the allocator.
// Fix: stage EtS via __builtin_amdgcn_global_load_lds (DMA, ZERO staging
// VGPRs / no ds_write). Etg rows are 512B-contiguous -> per wave-issue the
// LDS dest is uniform-base + lane*16B (the HW pattern, m97/m104). 8x8 tile
// retained (1.0 LDS-byte/fma, R4-proven VGPR=128 clean).
// Per tile: compute(8K cyc) -> barrier -> 8 DMA issues/wave -> barrier
// (vmcnt(0) drain) -> next tile. 68KB LDS -> 2 blocks/CU.
// Numerics FROZEN (absmax 0.0 R1-R8): sequential fma c=0..63 per (n,k);
// d = fmaf(-2,acc,fl(zn+ek)); ascending-k strict <; R4-verified lane
// mapping, k-decode, u64 lexicographic reduce; frozen zn/epilogue/loss.
// ---------------------------------------------------------------------------
__global__ __launch_bounds__(256, 2) void vq_main(const float* __restrict__ Z,
                                                  const float* __restrict__ E,
                                                  const float* __restrict__ Etg,
                                                  const float* __restrict__ ek,
                                                  float* __restrict__ out,
                                                  float* __restrict__ partials) {
#pragma clang fp contract(off)
    __shared__ float Zt[C * MT];     // [c][n_local]  32 KB
    __shared__ float EtS[C * KT];    // [c][k_local]  32 KB
    __shared__ float znbuf[MT];
    __shared__ u64 red[4][8][8];     // [wave][i_l][m]

    const int t = threadIdx.x;
    const int wave = t >> 6, lane = t & 63;
    const int n0 = blockIdx.x * MT;
    const int b = n0 >> 12;
    const int hw0 = n0 & 4095;
    const float* zbase = Z + b * (C * HW) + hw0;

    // ---- stage Zt (coalesced; Z is already [c][n]-contiguous) ------------
#pragma unroll
    for (int r = 0; r < 8; ++r) {
        int idx4 = r * 256 + t;
        int c = idx4 >> 5, n4 = idx4 & 31;
        float4 v = *(const float4*)(zbase + c * HW + n4 * 4);
        *(float4*)(&Zt[c * MT + n4 * 4]) = v;
    }
    // ---- stage EtS tile 0 via DMA: issue q = wave*8+p covers EtS rows
    // {2q,2q+1} (1KB). LDS base uniform per wave-issue; HW dest =
    // base + lane*16B which matches row-linear layout exactly. ------------
#pragma unroll
    for (int p = 0; p < 8; ++p) {
        int q = wave * 8 + p;
        int c = 2 * q + (lane >> 5);
        const float* gsrc = Etg + c * K + (lane & 31) * 4;
        __builtin_amdgcn_global_load_lds((gas_ptr)gsrc, (las_ptr)&EtS[q * 256],
                                         16, 0, 0);
    }
    __syncthreads();   // drains vmcnt: Zt and EtS tile0 ready

    // ---- zn per row (numpy pairwise-8 order, FROZEN) ----
    if (t < MT) {
        float r8[8];
#pragma unroll
        for (int j = 0; j < 8; ++j) { float v = Zt[j * MT + t]; r8[j] = v * v; }
#pragma unroll
        for (int i = 1; i < 8; ++i)
#pragma unroll
            for (int j = 0; j < 8; ++j) { float v = Zt[(i * 8 + j) * MT + t]; r8[j] += v * v; }
        znbuf[t] = ((r8[0] + r8[1]) + (r8[2] + r8[3])) + ((r8[4] + r8[5]) + (r8[6] + r8[7]));
    }
    __syncthreads();

    const int i_l = lane & 7, j_l = lane >> 3;
    const int ig = ((wave & 1) << 3) | i_l;    // n-group 0..15 (rows ig*8..+8)
    const int jg = ((wave >> 1) << 3) | j_l;   // k-group 0..15 (codes jg*8..+8)

    float znm[8];
#pragma unroll
    for (int m = 0; m < 8; ++m) znm[m] = znbuf[ig * 8 + m];

    float dmin[8];
    int qb[8];
#pragma unroll
    for (int m = 0; m < 8; ++m) { dmin[m] = __builtin_inff(); qb[m] = 0; }

#pragma unroll 1
    for (int tile = 0; tile < NTILES; ++tile) {
        float ekq[8];
        {
            const float* ekp = ek + tile * KT + jg * 8;
            float4 a = *(const float4*)ekp;
            float4 bq = *(const float4*)(ekp + 4);
            ekq[0] = a.x;  ekq[1] = a.y;  ekq[2] = a.z;  ekq[3] = a.w;
            ekq[4] = bq.x; ekq[5] = bq.y; ekq[6] = bq.z; ekq[7] = bq.w;
        }

        float acc[8][8];
#pragma unroll
        for (int m = 0; m < 8; ++m)
#pragma unroll
            for (int q = 0; q < 8; ++q) acc[m][q] = 0.0f;

#pragma unroll 4
        for (int c = 0; c < C; ++c) {
            float4 za = *(const float4*)(&Zt[c * MT + ig * 8]);
            float4 zb = *(const float4*)(&Zt[c * MT + ig * 8 + 4]);
            float4 ea = *(const float4*)(&EtS[c * KT + jg * 8]);
            float4 eb = *(const float4*)(&EtS[c * KT + jg * 8 + 4]);
            float zm[8] = {za.x, za.y, za.z, za.w, zb.x, zb.y, zb.z, zb.w};
            float eq[8] = {ea.x, ea.y, ea.z, ea.w, eb.x, eb.y, eb.z, eb.w};
#pragma unroll
            for (int m = 0; m < 8; ++m)
#pragma unroll
                for (int q = 0; q < 8; ++q)
                    acc[m][q] = __builtin_fmaf(zm[m], eq[q], acc[m][q]);
        }

        const int qbase = tile * 8;
#pragma unroll
        for (int m = 0; m < 8; ++m)
#pragma unroll
            for (int q = 0; q < 8; ++q) {
                float A = znm[m] + ekq[q];                     // fl(zn+ek)
                float d = __builtin_fmaf(-2.0f, acc[m][q], A); // == fl(A-2a), 2a exact
                if (d < dmin[m]) { dmin[m] = d; qb[m] = qbase + q; }
            }

        __syncthreads();   // all waves done READING EtS
        if (tile + 1 < NTILES) {
            const float* src = Etg + (tile + 1) * KT;
#pragma unroll
            for (int p = 0; p < 8; ++p) {
                int q = wave * 8 + p;
                int c = 2 * q + (lane >> 5);
                const float* gsrc = src + c * K + (lane & 31) * 4;
                __builtin_amdgcn_global_load_lds((gas_ptr)gsrc,
                                                 (las_ptr)&EtS[q * 256],
                                                 16, 0, 0);
            }
        }
        __syncthreads();   // vmcnt(0) drain before barrier -> EtS ready
    }

    // decode per-thread k, pack to (mono(d),k), reduce (R4-verified path)
    u64 bestp[8];
#pragma unroll
    for (int m = 0; m < 8; ++m) {
        int q8 = qb[m];
        int k = ((q8 >> 3) << 7) + jg * 8 + (q8 & 7);
        bestp[m] = packdk(dmin[m], k);
    }
#pragma unroll
    for (int m = 0; m < 8; ++m) {
        u64 v = bestp[m];
#pragma unroll
        for (int mask = 8; mask <= 32; mask <<= 1) {
            u64 o = __shfl_xor(v, mask, 64);
            v = o < v ? o : v;
        }
        bestp[m] = v;
    }
    if (j_l == 0) {
#pragma unroll
        for (int m = 0; m < 8; ++m) red[wave][i_l][m] = bestp[m];
    }
    __syncthreads();

    // ---- fused epilogue: thread t<128 owns row t (FROZEN body/order) ----
    if (t < MT) {
        int igg = t >> 3, m = t & 7;
        int ihalf = igg >> 3, iw = igg & 7;   // waves {ihalf, ihalf+2} hold it
        u64 a = red[ihalf][iw][m];
        u64 b2 = red[ihalf + 2][iw][m];
        u64 v = b2 < a ? b2 : a;
        int best = (int)(v & 0xFFFFFFFFu);
        int n = n0 + t;
        out[OUT0 + n] = (float)best;

        const float4* eb4 = (const float4*)(E + best * C);
        float* o0 = out + b * (C * HW) + hw0 + t;
        float ls = 0.0f;
#pragma unroll
        for (int c4 = 0; c4 < 16; ++c4) {
            float4 e4 = eb4[c4];
            int cb = c4 * 4;
            float z0 = Zt[(cb + 0) * MT + t], z1 = Zt[(cb + 1) * MT + t];
            float z2 = Zt[(cb + 2) * MT + t], z3 = Zt[(cb + 3) * MT + t];
            float f0 = e4.x - z0; o0[(cb + 0) * HW] = z0 + f0; ls += f0 * f0;
            float f1 = e4.y - z1; o0[(cb + 1) * HW] = z1 + f1; ls += f1 * f1;
            float f2 = e4.z - z2; o0[(cb + 2) * HW] = z2 + f2; ls += f2 * f2;
            float f3 = e4.w - z3; o0[(cb + 3) * HW] = z3 + f3; ls += f3 * f3;
        }
#pragma unroll
        for (int off = 32; off > 0; off >>= 1) ls += __shfl_xor(ls, off, 64);
        if ((t & 63) == 0) partials[n >> 6] = ls;
    }
}

// ---------------------------------------------------------------------------
// Fallback path kernels (tiny ws): R2/R4 structure, FROZEN.
// ---------------------------------------------------------------------------
__global__ __launch_bounds__(256) void ek_kernel(const float* __restrict__ E,
                                                 float* __restrict__ ek) {
#pragma clang fp contract(off)
    int k = blockIdx.x * 256 + threadIdx.x;
    if (k >= K) return;
    const float* e = E + k * C;
    float r[8];
#pragma unroll
    for (int j = 0; j < 8; ++j) { float v = e[j]; r[j] = v * v; }
#pragma unroll
    for (int i = 8; i < C; i += 8) {
#pragma unroll
        for (int j = 0; j < 8; ++j) { float v = e[i + j]; r[j] += v * v; }
    }
    ek[k] = ((r[0] + r[1]) + (r[2] + r[3])) + ((r[4] + r[5]) + (r[6] + r[7]));
}

__global__ __launch_bounds__(256, 4) void vq_combined(const float* __restrict__ Z,
                                                      const float* __restrict__ E,
                                                      const float* __restrict__ ek,
                                                      float* __restrict__ out,
                                                      float* __restrict__ partials) {
#pragma clang fp contract(off)
    int n = blockIdx.x * 256 + threadIdx.x;
    int b = n >> 12;
    int hw = n & 4095;
    const float* zp = Z + b * (C * HW) + hw;

    float z[C];
#pragma unroll
    for (int c = 0; c < C; ++c) z[c] = zp[c * HW];
    float zn;
    {
        float r[8];
#pragma unroll
        for (int j = 0; j < 8; ++j) r[j] = z[j] * z[j];
#pragma unroll
        for (int i = 8; i < C; i += 8) {
#pragma unroll
            for (int j = 0; j < 8; ++j) r[j] += z[i + j] * z[i + j];
        }
        zn = ((r[0] + r[1]) + (r[2] + r[3])) + ((r[4] + r[5]) + (r[6] + r[7]));
    }

    float dmin = __builtin_inff();
    int best = 0;
#pragma unroll 1
    for (int k = 0; k < K; k += 4) {
        const float* e0 = E + k * C;
        float a0 = 0.0f, a1 = 0.0f, a2 = 0.0f, a3 = 0.0f;
#pragma unroll
        for (int c = 0; c < C; ++c) {
            float zc = z[c];
            a0 = __builtin_fmaf(zc, e0[c], a0);
            a1 = __builtin_fmaf(zc, e0[C + c], a1);
            a2 = __builtin_fmaf(zc, e0[2 * C + c], a2);
            a3 = __builtin_fmaf(zc, e0[3 * C + c], a3);
        }
        float A0 = zn + ek[k],     A1 = zn + ek[k + 1];
        float A2 = zn + ek[k + 2], A3 = zn + ek[k + 3];
        float d0 = A0 - 2.0f * a0, d1 = A1 - 2.0f * a1;
        float d2 = A2 - 2.0f * a2, d3 = A3 - 2.0f * a3;
        if (d0 < dmin) { dmin = d0; best = k; }
        if (d1 < dmin) { dmin = d1; best = k + 1; }
        if (d2 < dmin) { dmin = d2; best = k + 2; }
        if (d3 < dmin) { dmin = d3; best = k + 3; }
    }

    const float4* eb4 = (const float4*)(E + best * C);
    float* o0 = out + b * (C * HW) + hw;
    float ls = 0.0f;
#pragma unroll
    for (int c4 = 0; c4 < 16; ++c4) {
        float4 e4 = eb4[c4];
        int cb = c4 * 4;
        float f0 = e4.x - z[cb + 0]; o0[(cb + 0) * HW] = z[cb + 0] + f0; ls += f0 * f0;
        float f1 = e4.y - z[cb + 1]; o0[(cb + 1) * HW] = z[cb + 1] + f1; ls += f1 * f1;
        float f2 = e4.z - z[cb + 2]; o0[(cb + 2) * HW] = z[cb + 2] + f2; ls += f2 * f2;
        float f3 = e4.w - z[cb + 3]; o0[(cb + 3) * HW] = z[cb + 3] + f3; ls += f3 * f3;
    }
    out[OUT0 + n] = (float)best;
#pragma unroll
    for (int off = 32; off > 0; off >>= 1) ls += __shfl_xor(ls, off, 64);
    if ((threadIdx.x & 63) == 0) partials[n >> 6] = ls;
}

// ---------------------------------------------------------------------------
// Final loss reduction in fp64 (FROZEN).
// ---------------------------------------------------------------------------
__global__ __launch_bounds__(256) void loss_kernel(const float* __restrict__ partials,
                                                   float* __restrict__ out) {
    __shared__ double sm[256];
    int t = threadIdx.x;
    double s = 0.0;
    for (int i = t; i < (N_TOTAL / 64); i += 256) s += (double)partials[i];
    sm[t] = s;
    __syncthreads();
    for (int o = 128; o > 0; o >>= 1) {
        if (t < o) sm[t] += sm[t + o];
        __syncthreads();
    }
    if (t == 0) {
        float m = (float)(sm[0] * (1.0 / 8388608.0));
        float loss = m + 0.25f * m;
        out[OUT0 + N_TOTAL] = loss;
    }
}

extern "C" void kernel_launch(void* const* d_in, const int* in_sizes, int n_in,
                              void* d_out, int out_size, void* d_ws, size_t ws_size,
                              hipStream_t stream) {
    const float* Z = (const float*)d_in[0];
    const float* E = (const float*)d_in[1];
    float* out = (float*)d_out;
    float* ws = (float*)d_ws;
    float* ek = ws + WS_EK;
    float* partials = ws + WS_PARTIALS;

    if (ws_size >= (size_t)WS_NEED_FLOATS * sizeof(float)) {
        float* Etg = ws + WS_ETG;
        hipLaunchKernelGGL(eprep_kernel, dim3(K / 256), dim3(256), 0, stream,
                           E, Etg, ek);
        hipLaunchKernelGGL(vq_main, dim3(N_TOTAL / MT), dim3(256), 0, stream,
                           Z, E, Etg, ek, out, partials);
    } else {
        hipLaunchKernelGGL(ek_kernel, dim3(4), dim3(256), 0, stream, E, ek);
        hipLaunchKernelGGL(vq_combined, dim3(N_TOTAL / 256), dim3(256), 0, stream,
                           Z, E, ek, out, partials);
    }
    hipLaunchKernelGGL(loss_kernel, dim3(1), dim3(256), 0, stream, partials, out);
}